// Round 3
// baseline (150.973 us; speedup 1.0000x reference)
//
#include <hip/hip_runtime.h>

#define S_LEN 2048
#define HID   1024
#define NHEAD 16
#define NKVH  4
#define HDIM  64
#define NPROJ 1536   // projection output cols: 1024 Q + 256 K + 256 V
#define QKSTR 1280   // qkv buffer row stride: Q(1024) + K(256); V goes to vT transposed

typedef __bf16 bf16x8 __attribute__((ext_vector_type(8)));
typedef __bf16 bf16x4 __attribute__((ext_vector_type(4)));
typedef float  f32x4  __attribute__((ext_vector_type(4)));

typedef const __attribute__((address_space(1))) void* gas_ptr;
typedef __attribute__((address_space(3))) void*       las_ptr;

// scale = (1/sqrt(1024)) * log2(e): fold softmax scale + base-2 conversion into Q
#define QSCALE 0.04508422f

__device__ __forceinline__ unsigned short f2bf(float f) {
    unsigned u = __builtin_bit_cast(unsigned, f);
    u = u + 0x7FFFu + ((u >> 16) & 1u);   // round-to-nearest-even
    return (unsigned short)(u >> 16);
}

// ---------------- fp32 -> bf16 conversion of x and all weights ----------------
__global__ __launch_bounds__(256) void cvt_all(
    const float* __restrict__ x,  const float* __restrict__ wq,
    const float* __restrict__ wk, const float* __restrict__ wv,
    unsigned short* __restrict__ xbf, unsigned short* __restrict__ wbf)
{
    const long nx  = (long)S_LEN * HID;     // 2097152
    const long nwq = (long)HID * HID;       // 1048576
    const long nwk = (long)256 * HID;       // 262144
    long i = (long)(blockIdx.x * 256 + threadIdx.x) * 4;
    const float* src; unsigned short* dst;
    if (i < nx)                  { src = x  + i;                 dst = xbf + i; }
    else if (i < nx + nwq)       { long j = i - nx;              src = wq + j; dst = wbf + j; }
    else if (i < nx + nwq + nwk) { long j = i - nx - nwq;        src = wk + j; dst = wbf + nwq + j; }
    else                         { long j = i - nx - nwq - nwk;  src = wv + j; dst = wbf + nwq + nwk + j; }
    float4 v = *(const float4*)src;
    ushort4 o; o.x = f2bf(v.x); o.y = f2bf(v.y); o.z = f2bf(v.z); o.w = f2bf(v.w);
    *(ushort4*)dst = o;
}

// ---------------- QKV projection (unchanged from passing R2) ----------------
__global__ __launch_bounds__(256, 2) void proj_gemm(
    const unsigned short* __restrict__ xbf,
    const unsigned short* __restrict__ wbf,
    unsigned short* __restrict__ qkv,
    unsigned short* __restrict__ vT)
{
    __shared__ unsigned short At[2][64 * 64];
    __shared__ unsigned short Bt[2][96 * 64];
    const int tid = threadIdx.x;
    const int w = tid >> 6, l = tid & 63;
    const int quad = l >> 4, lane16 = l & 15;
    const int m0 = blockIdx.y * 64, n0 = blockIdx.x * 96;
    const int wm = (w & 1) * 32, wn = (w >> 1) * 48;

    const int srow = l >> 3;
    const int scol = ((l & 7) ^ srow) * 8;

    f32x4 acc[2][3] = {};

    #define STAGE(KT, BUF)                                                              \
        do {                                                                            \
            _Pragma("unroll")                                                           \
            for (int c = 0; c < 2; ++c) {                                               \
                const int rbase = w * 16 + c * 8;                                       \
                const unsigned short* ga =                                              \
                    xbf + (long)(m0 + rbase + srow) * HID + (KT) + scol;                \
                __builtin_amdgcn_global_load_lds((gas_ptr)ga,                           \
                    (las_ptr)&At[BUF][rbase * 64], 16, 0, 0);                           \
            }                                                                           \
            _Pragma("unroll")                                                           \
            for (int c = 0; c < 3; ++c) {                                               \
                const int rbase = w * 24 + c * 8;                                       \
                const unsigned short* gb =                                              \
                    wbf + (long)(n0 + rbase + srow) * HID + (KT) + scol;                \
                __builtin_amdgcn_global_load_lds((gas_ptr)gb,                           \
                    (las_ptr)&Bt[BUF][rbase * 64], 16, 0, 0);                           \
            }                                                                           \
        } while (0)

    STAGE(0, 0);

    for (int i = 0; i < 16; ++i) {
        const int cur = i & 1;
        __syncthreads();
        if (i + 1 < 16) STAGE((i + 1) * 64, cur ^ 1);

        #pragma unroll
        for (int ks = 0; ks < 2; ++ks) {
            const int swz = ((ks * 4 + quad) ^ (lane16 & 7)) * 8;
            bf16x8 a[2], b[3];
            #pragma unroll
            for (int mi = 0; mi < 2; ++mi)
                a[mi] = *(const bf16x8*)&At[cur][(wm + mi * 16 + lane16) * 64 + swz];
            #pragma unroll
            for (int ni = 0; ni < 3; ++ni)
                b[ni] = *(const bf16x8*)&Bt[cur][(wn + ni * 16 + lane16) * 64 + swz];
            #pragma unroll
            for (int mi = 0; mi < 2; ++mi)
                #pragma unroll
                for (int ni = 0; ni < 3; ++ni)
                    acc[mi][ni] = __builtin_amdgcn_mfma_f32_16x16x32_bf16(a[mi], b[ni], acc[mi][ni], 0, 0, 0);
        }
    }
    #undef STAGE

    #pragma unroll
    for (int mi = 0; mi < 2; ++mi) {
        const int row = m0 + wm + mi * 16 + quad * 4;
        #pragma unroll
        for (int ni = 0; ni < 3; ++ni) {
            const int col = n0 + wn + ni * 16 + lane16;
            #pragma unroll
            for (int r = 0; r < 4; ++r) {
                const float v = acc[mi][ni][r];
                if (col < 1024)
                    qkv[(long)(row + r) * QKSTR + col] = f2bf(v * QSCALE);
                else if (col < 1280)
                    qkv[(long)(row + r) * QKSTR + col] = f2bf(v);
                else
                    vT[(long)(col - 1280) * S_LEN + (row + r)] = f2bf(v);
            }
        }
    }
}

// ---------------- flash attention (MFMA), causal, GQA rep=4 ----------------
// Round-9 change: BARRIER-FREE attn. The only reason for __syncthreads was
// cooperative K/V LDS staging; but each tile is 8KB (K) + 8KB (V) and the
// 4-wave intra-block reuse fits L1 (32KB). So each wave now loads its K/V
// MFMA fragments DIRECTLY from global into registers (addresses are the
// verbatim transcription of what LDS staging held — fragment layouts
// unchanged), single-buffered with load-after-last-use (WAR keeps order),
// prefetched one tile ahead. Removes: all barriers, all staging ds_writes,
// 16 of 22 ds-ops per wave-iteration. Waves free-run; the only LDS left is
// the wave-private P buffer (proven path, kept verbatim incl. the compiler
// fence). s_setprio(1) wraps both MFMA clusters (T5: +4-7% on free-running
// attn structures, m191).
#define KSTR 72   // LDS row stride (ushorts): multiple of 8 -> 16B-aligned b128
__global__ __launch_bounds__(256, 2) void attn(
    const unsigned short* __restrict__ qkv,
    const unsigned short* __restrict__ vT,
    float* __restrict__ out)
{
    __shared__ unsigned short Pb[4 * 16 * KSTR];    // per-wave P [qrow][kv] (swizzled)

    const int tid = threadIdx.x;
    const int w = tid >> 6, l = tid & 63;
    const int quad = l >> 4, lane16 = l & 15;
    const int bx = blockIdx.x, by = blockIdx.y;
    const int qt = (by & 8) ? (31 - bx) : bx;       // balanced pairing remap
    const int h  = by;
    const int kh = h >> 2;
    const int qcol = h * 64;
    const int kcol = 1024 + kh * 64;

    // Q fragments (m/n=lane&15, k=quad*8+j), Q pre-scaled by proj_gemm
    const long qrow = (long)(qt * 64 + w * 16 + lane16);
    bf16x8 qa0 = *(const bf16x8*)&qkv[qrow * QKSTR + qcol + quad * 8];
    bf16x8 qa1 = *(const bf16x8*)&qkv[qrow * QKSTR + qcol + 32 + quad * 8];

    f32x4 o[4] = {};
    float rsum[4] = {0.f, 0.f, 0.f, 0.f};

    unsigned short* pw = &Pb[w * 16 * KSTR];

    // per-lane global bases for direct K/V fragment loads
    // K frag (B-op): row = kt*64 + t*16+lane16 of qkv K-block, off = quad*8 (+32)
    // V frag (B-op): row d = kh*64 + t*16+lane16 of vT, col = kt*64 + ks*32 + quad*8
    const unsigned short* kbase = qkv + kcol;
    const unsigned short* vbase = vT + (long)(kh * 64) * S_LEN;

    bf16x8 kb[8], vb[8];

    #define LOADK(KT)                                                                   \
        do {                                                                            \
            _Pragma("unroll")                                                           \
            for (int t = 0; t < 4; ++t) {                                               \
                const long gr = (long)((KT) * 64 + t * 16 + lane16) * QKSTR;            \
                kb[2 * t]     = *(const bf16x8*)&kbase[gr + quad * 8];                  \
                kb[2 * t + 1] = *(const bf16x8*)&kbase[gr + 32 + quad * 8];             \
            }                                                                           \
        } while (0)

    #define LOADV(KT)                                                                   \
        do {                                                                            \
            _Pragma("unroll")                                                           \
            for (int ks = 0; ks < 2; ++ks)                                              \
                _Pragma("unroll")                                                       \
                for (int t = 0; t < 4; ++t) {                                           \
                    const long gv = (long)(t * 16 + lane16) * S_LEN +                   \
                                    (KT) * 64 + ks * 32 + quad * 8;                     \
                    vb[ks * 4 + t] = *(const bf16x8*)&vbase[gv];                        \
                }                                                                       \
        } while (0)

    LOADK(0);
    LOADV(0);

    for (int kt = 0; kt <= qt; ++kt) {
        // S^T = K Q^T  (64 kv x 16 q-rows); A = K (m=kv), B = Q (n=qrow)
        // C layout per tile t: row = kv = t*16 + quad*4 + r, col = qrow = lane16
        f32x4 sacc[4] = {};
        __builtin_amdgcn_s_setprio(1);
        #pragma unroll
        for (int t = 0; t < 4; ++t) {
            sacc[t] = __builtin_amdgcn_mfma_f32_16x16x32_bf16(kb[2 * t],     qa0, sacc[t], 0, 0, 0);
            sacc[t] = __builtin_amdgcn_mfma_f32_16x16x32_bf16(kb[2 * t + 1], qa1, sacc[t], 0, 0, 0);
        }
        __builtin_amdgcn_s_setprio(0);

        // prefetch next K tile into the (now consumed) kb regs; lands during
        // softmax + PV + next-iteration wait (WAR on kb orders vs MFMA use)
        if (kt < qt) LOADK(kt + 1);

        // causal mask on diagonal tile: kv > qrow  (both local to this 64-block)
        if (kt == qt) {
            #pragma unroll
            for (int t = 0; t < 4; ++t) {
                const int kvw = t * 16 + quad * 4;
                #pragma unroll
                for (int r = 0; r < 4; ++r)
                    if (kvw + r > w * 16 + lane16) sacc[t][r] = -3.0e38f;
            }
        }

        // p = exp2(s) directly (scores bounded; masked -> +0). Lane's 4 values
        // per t are contiguous kv of q-row lane16: one bf16x4 store per t.
        #pragma unroll
        for (int t = 0; t < 4; ++t) {
            const float p0 = __builtin_amdgcn_exp2f(sacc[t][0]);
            const float p1 = __builtin_amdgcn_exp2f(sacc[t][1]);
            const float p2 = __builtin_amdgcn_exp2f(sacc[t][2]);
            const float p3 = __builtin_amdgcn_exp2f(sacc[t][3]);
            rsum[t] += (p0 + p1) + (p2 + p3);
            bf16x4 pk;
            pk[0] = (__bf16)p0; pk[1] = (__bf16)p1;
            pk[2] = (__bf16)p2; pk[3] = (__bf16)p3;
            *(bf16x4*)&pw[lane16 * KSTR + ((t * 16 + quad * 4) ^ ((lane16 & 12) << 1))] = pk;
        }

        // Compiler fence: forbid hoisting the PV ds_reads above the P ds_writes
        // (per-wave DS pipe is in-order in HW; only compiler motion is unsafe).
        asm volatile("" ::: "memory");
        __builtin_amdgcn_sched_barrier(0);

        // O += P V   (A = P [m=qrow][k=kv], B = V^T [n=d][k=kv])
        bf16x8 pa0 = *(const bf16x8*)&pw[lane16 * KSTR + ((quad * 8)      ^ ((lane16 & 12) << 1))];
        bf16x8 pa1 = *(const bf16x8*)&pw[lane16 * KSTR + ((32 + quad * 8) ^ ((lane16 & 12) << 1))];
        __builtin_amdgcn_s_setprio(1);
        #pragma unroll
        for (int t = 0; t < 4; ++t)
            o[t] = __builtin_amdgcn_mfma_f32_16x16x32_bf16(pa0, vb[t], o[t], 0, 0, 0);
        #pragma unroll
        for (int t = 0; t < 4; ++t)
            o[t] = __builtin_amdgcn_mfma_f32_16x16x32_bf16(pa1, vb[4 + t], o[t], 0, 0, 0);
        __builtin_amdgcn_s_setprio(0);

        // prefetch next V tile (WAR on vb orders vs the PV MFMAs just issued)
        if (kt < qt) LOADV(kt + 1);
    }
    #undef LOADK
    #undef LOADV

    // row-sum: lane's partials cover a full q-row chunk (qrow=lane16);
    // sum the 4 quad-chunks (lanes l^16, l^32), then broadcast 1/sum to the
    // O-accumulator layout (row = quad*4 + r).
    float total = (rsum[0] + rsum[1]) + (rsum[2] + rsum[3]);
    total += __shfl_xor(total, 16);
    total += __shfl_xor(total, 32);
    const float invt = 1.0f / total;
    float inv[4];
    #pragma unroll
    for (int r = 0; r < 4; ++r)
        inv[r] = __shfl(invt, quad * 4 + r);

    const int orow = qt * 64 + w * 16 + quad * 4;
    #pragma unroll
    for (int t = 0; t < 4; ++t) {
        const int col = h * 64 + t * 16 + lane16;
        #pragma unroll
        for (int r = 0; r < 4; ++r)
            out[(long)(orow + r) * (NHEAD * HDIM) + col] = o[t][r] * inv[r];
    }
}

extern "C" void kernel_launch(void* const* d_in, const int* in_sizes, int n_in,
                              void* d_out, int out_size, void* d_ws, size_t ws_size,
                              hipStream_t stream) {
    const float* x  = (const float*)d_in[0];
    const float* wq = (const float*)d_in[1];
    const float* wk = (const float*)d_in[2];
    const float* wv = (const float*)d_in[3];
    float* out = (float*)d_out;

    unsigned short* xbf = (unsigned short*)d_ws;                 // 2048*1024
    unsigned short* wbf = xbf + (size_t)S_LEN * HID;             // 1536*1024
    unsigned short* qkv = wbf + (size_t)NPROJ * HID;             // 2048*1280 (Q+K)
    unsigned short* vT  = qkv + (size_t)S_LEN * QKSTR;           // 256*2048  (V^T)

    cvt_all<<<dim3(3584), dim3(256), 0, stream>>>(x, wq, wk, wv, xbf, wbf);
    proj_gemm<<<dim3(16, 32), dim3(256), 0, stream>>>(xbf, wbf, qkv, vT);
    attn<<<dim3(32, 16), dim3(256), 0, stream>>>(qkv, vT, out);
}

// Round 4
// 115.826 us; speedup vs baseline: 1.3034x; 1.3034x over previous
//
#include <hip/hip_runtime.h>

#define S_LEN 2048
#define HID   1024
#define NHEAD 16
#define NKVH  4
#define HDIM  64
#define NPROJ 1536   // projection output cols: 1024 Q + 256 K + 256 V
#define QKSTR 1280   // qkv buffer row stride: Q(1024) + K(256); V goes to vT transposed

typedef __bf16 bf16x8 __attribute__((ext_vector_type(8)));
typedef __bf16 bf16x4 __attribute__((ext_vector_type(4)));
typedef __bf16 bf16x2 __attribute__((ext_vector_type(2)));
typedef float  f32x4  __attribute__((ext_vector_type(4)));
typedef unsigned u32x4 __attribute__((ext_vector_type(4)));

typedef const __attribute__((address_space(1))) void* gas_ptr;
typedef __attribute__((address_space(3))) void*       las_ptr;

// scale = (1/sqrt(1024)) * log2(e): fold softmax scale + base-2 conversion into Q
#define QSCALE 0.04508422f

__device__ __forceinline__ unsigned short f2bf(float f) {
    unsigned u = __builtin_bit_cast(unsigned, f);
    u = u + 0x7FFFu + ((u >> 16) & 1u);   // round-to-nearest-even
    return (unsigned short)(u >> 16);
}

// ---------------- fp32 -> bf16 conversion of x and all weights ----------------
__global__ __launch_bounds__(256) void cvt_all(
    const float* __restrict__ x,  const float* __restrict__ wq,
    const float* __restrict__ wk, const float* __restrict__ wv,
    unsigned short* __restrict__ xbf, unsigned short* __restrict__ wbf)
{
    const long nx  = (long)S_LEN * HID;     // 2097152
    const long nwq = (long)HID * HID;       // 1048576
    const long nwk = (long)256 * HID;       // 262144
    long i = (long)(blockIdx.x * 256 + threadIdx.x) * 4;
    const float* src; unsigned short* dst;
    if (i < nx)                  { src = x  + i;                 dst = xbf + i; }
    else if (i < nx + nwq)       { long j = i - nx;              src = wq + j; dst = wbf + j; }
    else if (i < nx + nwq + nwk) { long j = i - nx - nwq;        src = wk + j; dst = wbf + nwq + j; }
    else                         { long j = i - nx - nwq - nwk;  src = wv + j; dst = wbf + nwq + nwk + j; }
    float4 v = *(const float4*)src;
    ushort4 o; o.x = f2bf(v.x); o.y = f2bf(v.y); o.z = f2bf(v.z); o.w = f2bf(v.w);
    *(ushort4*)dst = o;
}

// ---------------- QKV projection (unchanged from passing R2) ----------------
__global__ __launch_bounds__(256, 2) void proj_gemm(
    const unsigned short* __restrict__ xbf,
    const unsigned short* __restrict__ wbf,
    unsigned short* __restrict__ qkv,
    unsigned short* __restrict__ vT)
{
    __shared__ unsigned short At[2][64 * 64];
    __shared__ unsigned short Bt[2][96 * 64];
    const int tid = threadIdx.x;
    const int w = tid >> 6, l = tid & 63;
    const int quad = l >> 4, lane16 = l & 15;
    const int m0 = blockIdx.y * 64, n0 = blockIdx.x * 96;
    const int wm = (w & 1) * 32, wn = (w >> 1) * 48;

    const int srow = l >> 3;
    const int scol = ((l & 7) ^ srow) * 8;

    f32x4 acc[2][3] = {};

    #define STAGE(KT, BUF)                                                              \
        do {                                                                            \
            _Pragma("unroll")                                                           \
            for (int c = 0; c < 2; ++c) {                                               \
                const int rbase = w * 16 + c * 8;                                       \
                const unsigned short* ga =                                              \
                    xbf + (long)(m0 + rbase + srow) * HID + (KT) + scol;                \
                __builtin_amdgcn_global_load_lds((gas_ptr)ga,                           \
                    (las_ptr)&At[BUF][rbase * 64], 16, 0, 0);                           \
            }                                                                           \
            _Pragma("unroll")                                                           \
            for (int c = 0; c < 3; ++c) {                                               \
                const int rbase = w * 24 + c * 8;                                       \
                const unsigned short* gb =                                              \
                    wbf + (long)(n0 + rbase + srow) * HID + (KT) + scol;                \
                __builtin_amdgcn_global_load_lds((gas_ptr)gb,                           \
                    (las_ptr)&Bt[BUF][rbase * 64], 16, 0, 0);                           \
            }                                                                           \
        } while (0)

    STAGE(0, 0);

    for (int i = 0; i < 16; ++i) {
        const int cur = i & 1;
        __syncthreads();
        if (i + 1 < 16) STAGE((i + 1) * 64, cur ^ 1);

        #pragma unroll
        for (int ks = 0; ks < 2; ++ks) {
            const int swz = ((ks * 4 + quad) ^ (lane16 & 7)) * 8;
            bf16x8 a[2], b[3];
            #pragma unroll
            for (int mi = 0; mi < 2; ++mi)
                a[mi] = *(const bf16x8*)&At[cur][(wm + mi * 16 + lane16) * 64 + swz];
            #pragma unroll
            for (int ni = 0; ni < 3; ++ni)
                b[ni] = *(const bf16x8*)&Bt[cur][(wn + ni * 16 + lane16) * 64 + swz];
            #pragma unroll
            for (int mi = 0; mi < 2; ++mi)
                #pragma unroll
                for (int ni = 0; ni < 3; ++ni)
                    acc[mi][ni] = __builtin_amdgcn_mfma_f32_16x16x32_bf16(a[mi], b[ni], acc[mi][ni], 0, 0, 0);
        }
    }
    #undef STAGE

    #pragma unroll
    for (int mi = 0; mi < 2; ++mi) {
        const int row = m0 + wm + mi * 16 + quad * 4;
        #pragma unroll
        for (int ni = 0; ni < 3; ++ni) {
            const int col = n0 + wn + ni * 16 + lane16;
            #pragma unroll
            for (int r = 0; r < 4; ++r) {
                const float v = acc[mi][ni][r];
                if (col < 1024)
                    qkv[(long)(row + r) * QKSTR + col] = f2bf(v * QSCALE);
                else if (col < 1280)
                    qkv[(long)(row + r) * QKSTR + col] = f2bf(v);
                else
                    vT[(long)(col - 1280) * S_LEN + (row + r)] = f2bf(v);
            }
        }
    }
}

// ---------------- flash attention (MFMA), causal, GQA rep=4 ----------------
// R4: back to the R2-proven LDS-staged K/V structure (coalesced staging,
// reg-prefetch one tile ahead, one barrier/iter, double-buffered).
// ONE change: the P (softmax probs) LDS round-trip is replaced by an
// in-register cross-lane butterfly. After transposed QK^T (S^T = K Q^T),
// lane (quad Q, lane16 L) holds P[L][kv = t*16 + Q*4 + r]. PV's A-fragment
// needs P[L][kv = ks*32 + Q*8 + j]. Packing pairs into u32s
// h[t*2+p] = (P[t*16+Q*4+2p], +1), the required permutation is
//   n[ks][c] = h[(2ks+(Q>>1))*2 + (c&1)]  from source quad (Q&1)*2 + (c>>1)
// i.e. 16 __shfl + 8 selects within the 4-lane group {L, L+16, L+32, L+48}.
// This removes the serialized ds_write->fence->ds_read chain, all its bank
// conflicts (R3 measured 1.35M conflict cycles from this path alone), and
// 9KB LDS (45->36KB: block capacity 3->4 for tail rebalancing).
// s_setprio(1) wraps both MFMA clusters (T5, +4-7% attn per m191).
#define KSTR 72   // LDS row stride (ushorts): multiple of 8 -> 16B-aligned b128
__global__ __launch_bounds__(256, 3) void attn(
    const unsigned short* __restrict__ qkv,
    const unsigned short* __restrict__ vT,
    float* __restrict__ out)
{
    __shared__ unsigned short Kt[2][64 * KSTR];     // K tile  [kv][d]
    __shared__ unsigned short Vt[2][64 * KSTR];     // V^T tile [d][kv]

    const int tid = threadIdx.x;
    const int w = tid >> 6, l = tid & 63;
    const int quad = l >> 4, lane16 = l & 15;
    const int bx = blockIdx.x, by = blockIdx.y;
    const int qt = (by & 8) ? (31 - bx) : bx;       // balanced pairing remap
    const int h  = by;
    const int kh = h >> 2;
    const int qcol = h * 64;
    const int kcol = 1024 + kh * 64;

    // Q fragments (m/n=lane&15, k=quad*8+j), Q pre-scaled by proj_gemm
    const long qrow = (long)(qt * 64 + w * 16 + lane16);
    bf16x8 qa0 = *(const bf16x8*)&qkv[qrow * QKSTR + qcol + quad * 8];
    bf16x8 qa1 = *(const bf16x8*)&qkv[qrow * QKSTR + qcol + 32 + quad * 8];

    f32x4 o[4] = {};
    float rsum[4] = {0.f, 0.f, 0.f, 0.f};

    // staging coords: 256 thr x 16 ushorts cover each 64x64 tile
    const int sr = tid >> 2, ss = tid & 3;
    const long vrow = (long)(kh * 64 + sr) * S_LEN;

    // butterfly source lanes (constant): srcA = L + 32*(Q&1), srcB = srcA+16
    const int srcA = lane16 + ((l & 16) << 1);
    const int srcB = srcA + 16;
    const bool up = (l >= 32);                      // Q>>1

    // prologue: prefetch tile 0 into registers
    bf16x8 kr0, kr1, vr0, vr1;
    {
        const long gk = (long)sr * QKSTR + kcol + ss * 16;
        kr0 = *(const bf16x8*)&qkv[gk];
        kr1 = *(const bf16x8*)&qkv[gk + 8];
        const long gv = vrow + ss * 16;
        vr0 = *(const bf16x8*)&vT[gv];
        vr1 = *(const bf16x8*)&vT[gv + 8];
    }

    for (int kt = 0; kt <= qt; ++kt) {
        const int cur = kt & 1;
        // (A) store prefetched tile into buf[cur]; prefetch next into regs
        *(bf16x8*)&Kt[cur][sr * KSTR + ss * 16]     = kr0;
        *(bf16x8*)&Kt[cur][sr * KSTR + ss * 16 + 8] = kr1;
        *(bf16x8*)&Vt[cur][sr * KSTR + ss * 16]     = vr0;
        *(bf16x8*)&Vt[cur][sr * KSTR + ss * 16 + 8] = vr1;
        if (kt < qt) {                        // uniform branch
            const long gk = (long)((kt + 1) * 64 + sr) * QKSTR + kcol + ss * 16;
            kr0 = *(const bf16x8*)&qkv[gk];
            kr1 = *(const bf16x8*)&qkv[gk + 8];
            const long gv = vrow + (kt + 1) * 64 + ss * 16;
            vr0 = *(const bf16x8*)&vT[gv];
            vr1 = *(const bf16x8*)&vT[gv + 8];
        }
        __syncthreads();                      // (B) staging[cur] visible

        // S^T = K Q^T  (64 kv x 16 q-rows); A = K (m=kv), B = Q (n=qrow)
        // C layout per tile t: row = kv = t*16 + quad*4 + r, col = qrow = lane16
        f32x4 sacc[4] = {};
        __builtin_amdgcn_s_setprio(1);
        #pragma unroll
        for (int t = 0; t < 4; ++t) {
            bf16x8 kb0 = *(const bf16x8*)&Kt[cur][(t * 16 + lane16) * KSTR + quad * 8];
            bf16x8 kb1 = *(const bf16x8*)&Kt[cur][(t * 16 + lane16) * KSTR + 32 + quad * 8];
            sacc[t] = __builtin_amdgcn_mfma_f32_16x16x32_bf16(kb0, qa0, sacc[t], 0, 0, 0);
            sacc[t] = __builtin_amdgcn_mfma_f32_16x16x32_bf16(kb1, qa1, sacc[t], 0, 0, 0);
        }
        __builtin_amdgcn_s_setprio(0);

        // causal mask on diagonal tile: kv > qrow  (both local to this 64-block)
        if (kt == qt) {
            #pragma unroll
            for (int t = 0; t < 4; ++t) {
                const int kvw = t * 16 + quad * 4;
                #pragma unroll
                for (int r = 0; r < 4; ++r)
                    if (kvw + r > w * 16 + lane16) sacc[t][r] = -3.0e38f;
            }
        }

        // softmax: p = exp2(s) (scores bounded; masked -> +0); pack bf16 pairs
        unsigned h8[8];
        #pragma unroll
        for (int t = 0; t < 4; ++t) {
            const float p0 = __builtin_amdgcn_exp2f(sacc[t][0]);
            const float p1 = __builtin_amdgcn_exp2f(sacc[t][1]);
            const float p2 = __builtin_amdgcn_exp2f(sacc[t][2]);
            const float p3 = __builtin_amdgcn_exp2f(sacc[t][3]);
            rsum[t] += (p0 + p1) + (p2 + p3);
            bf16x2 lo, hi;
            lo[0] = (__bf16)p0; lo[1] = (__bf16)p1;
            hi[0] = (__bf16)p2; hi[1] = (__bf16)p3;
            h8[t * 2]     = __builtin_bit_cast(unsigned, lo);
            h8[t * 2 + 1] = __builtin_bit_cast(unsigned, hi);
        }

        // butterfly redistribution within the 4-lane quad group
        unsigned sA[8], sB[8];
        #pragma unroll
        for (int i = 0; i < 8; ++i) {
            sA[i] = __shfl(h8[i], srcA);
            sB[i] = __shfl(h8[i], srcB);
        }
        u32x4 w0, w1;
        w0[0] = up ? sA[2] : sA[0];  w0[1] = up ? sA[3] : sA[1];
        w0[2] = up ? sB[2] : sB[0];  w0[3] = up ? sB[3] : sB[1];
        w1[0] = up ? sA[6] : sA[4];  w1[1] = up ? sA[7] : sA[5];
        w1[2] = up ? sB[6] : sB[4];  w1[3] = up ? sB[7] : sB[5];
        const bf16x8 pa0 = __builtin_bit_cast(bf16x8, w0);
        const bf16x8 pa1 = __builtin_bit_cast(bf16x8, w1);

        // O += P V   (A = P [m=qrow][k=kv], B = V^T [n=d][k=kv])
        __builtin_amdgcn_s_setprio(1);
        #pragma unroll
        for (int t = 0; t < 4; ++t) {
            bf16x8 vb0 = *(const bf16x8*)&Vt[cur][(t * 16 + lane16) * KSTR + quad * 8];
            o[t] = __builtin_amdgcn_mfma_f32_16x16x32_bf16(pa0, vb0, o[t], 0, 0, 0);
        }
        #pragma unroll
        for (int t = 0; t < 4; ++t) {
            bf16x8 vb1 = *(const bf16x8*)&Vt[cur][(t * 16 + lane16) * KSTR + 32 + quad * 8];
            o[t] = __builtin_amdgcn_mfma_f32_16x16x32_bf16(pa1, vb1, o[t], 0, 0, 0);
        }
        __builtin_amdgcn_s_setprio(0);
    }

    // row-sum: lane's partials cover a full q-row chunk (qrow=lane16);
    // sum the 4 quad-chunks (lanes l^16, l^32), then broadcast 1/sum to the
    // O-accumulator layout (row = quad*4 + r).
    float total = (rsum[0] + rsum[1]) + (rsum[2] + rsum[3]);
    total += __shfl_xor(total, 16);
    total += __shfl_xor(total, 32);
    const float invt = 1.0f / total;
    float inv[4];
    #pragma unroll
    for (int r = 0; r < 4; ++r)
        inv[r] = __shfl(invt, quad * 4 + r);

    const int orow = qt * 64 + w * 16 + quad * 4;
    #pragma unroll
    for (int t = 0; t < 4; ++t) {
        const int col = h * 64 + t * 16 + lane16;
        #pragma unroll
        for (int r = 0; r < 4; ++r)
            out[(long)(orow + r) * (NHEAD * HDIM) + col] = o[t][r] * inv[r];
    }
}

extern "C" void kernel_launch(void* const* d_in, const int* in_sizes, int n_in,
                              void* d_out, int out_size, void* d_ws, size_t ws_size,
                              hipStream_t stream) {
    const float* x  = (const float*)d_in[0];
    const float* wq = (const float*)d_in[1];
    const float* wk = (const float*)d_in[2];
    const float* wv = (const float*)d_in[3];
    float* out = (float*)d_out;

    unsigned short* xbf = (unsigned short*)d_ws;                 // 2048*1024
    unsigned short* wbf = xbf + (size_t)S_LEN * HID;             // 1536*1024
    unsigned short* qkv = wbf + (size_t)NPROJ * HID;             // 2048*1280 (Q+K)
    unsigned short* vT  = qkv + (size_t)S_LEN * QKSTR;           // 256*2048  (V^T)

    cvt_all<<<dim3(3584), dim3(256), 0, stream>>>(x, wq, wk, wv, xbf, wbf);
    proj_gemm<<<dim3(16, 32), dim3(256), 0, stream>>>(xbf, wbf, qkv, vT);
    attn<<<dim3(32, 16), dim3(256), 0, stream>>>(qkv, vT, out);
}